// Round 18
// baseline (17219.156 us; speedup 1.0000x reference)
//
#include <hip/hip_runtime.h>
#include <hip/hip_bf16.h>

#define T_LEN 2048
#define N_IN 256
#define N_H 512
#define N_B 64

typedef float f32x4 __attribute__((ext_vector_type(4)));
typedef __bf16 bf16x8 __attribute__((ext_vector_type(8)));
typedef int i32x4 __attribute__((ext_vector_type(4)));

__device__ __forceinline__ unsigned short f2bf(float f) {
  union { float f; unsigned int i; } x; x.f = f;
  unsigned int r = x.i + 0x7fffu + ((x.i >> 16) & 1u);  // RNE
  return (unsigned short)(r >> 16);
}
__device__ __forceinline__ float sigm(float x) { return 1.0f / (1.0f + __expf(-x)); }
__device__ __forceinline__ float tanh_(float x) {
  float a = fabsf(x);
  float e = __expf(2.0f * a);
  float r = 1.0f - 2.0f / (e + 1.0f);
  return copysignf(r, x);
}
__device__ __forceinline__ bf16x8 cvt8(const float* __restrict__ p) {
  f32x4 a = *(const f32x4*)(const void*)p;
  f32x4 b = *(const f32x4*)(const void*)(p + 4);
  union { bf16x8 v; unsigned short u[8]; } r;
  #pragma unroll
  for (int j = 0; j < 4; ++j) { r.u[j] = f2bf(a[j]); r.u[j + 4] = f2bf(b[j]); }
  return r.v;
}

// ---- sc0 (XCD-L2 coherent, L1-bypass) inline-asm ops ----
__device__ __forceinline__ void st_u64_sc0(void* sb, int vb, unsigned long long v) {
  asm volatile("global_store_dwordx2 %0, %1, %2 sc0"
               :: "v"(vb), "v"(v), "s"(sb) : "memory");
}
// 16 pipelined dwordx4 loads (one L2 round-trip); vb = lane byte offset in buf
__device__ __forceinline__ void ld_h16_sc0(const void* sb, int vb, i32x4 f[16]) {
  int v0 = vb, v1 = vb + 4096, v2 = vb + 8192, v3 = vb + 12288;
  asm volatile(
    "global_load_dwordx4 %0, %16, %20 offset:0 sc0\n\t"
    "global_load_dwordx4 %1, %16, %20 offset:1024 sc0\n\t"
    "global_load_dwordx4 %2, %16, %20 offset:2048 sc0\n\t"
    "global_load_dwordx4 %3, %16, %20 offset:3072 sc0\n\t"
    "global_load_dwordx4 %4, %17, %20 offset:0 sc0\n\t"
    "global_load_dwordx4 %5, %17, %20 offset:1024 sc0\n\t"
    "global_load_dwordx4 %6, %17, %20 offset:2048 sc0\n\t"
    "global_load_dwordx4 %7, %17, %20 offset:3072 sc0\n\t"
    "global_load_dwordx4 %8, %18, %20 offset:0 sc0\n\t"
    "global_load_dwordx4 %9, %18, %20 offset:1024 sc0\n\t"
    "global_load_dwordx4 %10, %18, %20 offset:2048 sc0\n\t"
    "global_load_dwordx4 %11, %18, %20 offset:3072 sc0\n\t"
    "global_load_dwordx4 %12, %19, %20 offset:0 sc0\n\t"
    "global_load_dwordx4 %13, %19, %20 offset:1024 sc0\n\t"
    "global_load_dwordx4 %14, %19, %20 offset:2048 sc0\n\t"
    "global_load_dwordx4 %15, %19, %20 offset:3072 sc0\n\t"
    "s_waitcnt vmcnt(0)"
    : "=&v"(f[0]), "=&v"(f[1]), "=&v"(f[2]), "=&v"(f[3]),
      "=&v"(f[4]), "=&v"(f[5]), "=&v"(f[6]), "=&v"(f[7]),
      "=&v"(f[8]), "=&v"(f[9]), "=&v"(f[10]), "=&v"(f[11]),
      "=&v"(f[12]), "=&v"(f[13]), "=&v"(f[14]), "=&v"(f[15])
    : "v"(v0), "v"(v1), "v"(v2), "v"(v3), "s"(sb)
    : "memory");
}

// ws ints: [0]=total, [1]=gclaim, [8..16)=per-XCD slot ctr, [64..192)=gid cells (init -1)
// byte 4096: fast hbuf (4 groups x 4 bufs x 16384 B = 256 KB)
// byte 4096+262144: slow hbuf (same layout; == fast if !dual)
// Tag scheme (both sets): even-hcol u16 LSB = tau(t) = (t>>2)&1; h_t in buf t&3.
// Init: buf 0 = 0 (real h0, tag 0); bufs 1..3 = 0x0001 (tag 1 = invalid first cycle).
__global__ void lstm_init(int* __restrict__ ws, int nInts) {
  int i = blockIdx.x * 256 + threadIdx.x;
  if (i >= nInts) return;
  if (i < 1024) { ws[i] = (i >= 64 && i < 192) ? -1 : 0; return; }
  int j = i - 1024;
  ws[i] = ((j & 16383) < 4096) ? 0 : 0x00010001;
}

// 256 WGs x 128 thr; WGs self-organize into 4 groups of 16 SAME-XCD members via
// the XCC_ID registry; surplus WGs exit. Group gid owns batch rows 16*gid..+15,
// member m owns hidden cols 32m..32m+31. Tag-validated sc0 (XCD-L2) h exchange,
// watchdog fallback to the proven agent-scope path (producers dual-publish).
__global__ __launch_bounds__(128, 1) void lstm_persist(
    const float* __restrict__ X, const float* __restrict__ HID,
    const float* __restrict__ Wi, const float* __restrict__ bi,
    const float* __restrict__ Wg, const float* __restrict__ bg,
    const float* __restrict__ Wo, const float* __restrict__ bo,
    const float* __restrict__ Wout, const float* __restrict__ bout,
    float* __restrict__ out,
    unsigned short* __restrict__ hbF, unsigned short* __restrict__ hbS,
    int* __restrict__ reg, int dual)
{
  extern __shared__ unsigned short ldsw[];  // 147456 B weights + 1536 B scratch
  unsigned short* ldsh = ldsw + 96 * 768;
  __shared__ int sh_gid, sh_m;
  const int tid = threadIdx.x;

  // ---- registration: measure XCD, form same-XCD groups ----
  if (tid == 0) {
    unsigned xcc;
    asm volatile("s_getreg_b32 %0, hwreg(HW_REG_XCC_ID)" : "=s"(xcc));
    xcc &= 7;
    int s = __hip_atomic_fetch_add(&reg[8 + xcc], 1, __ATOMIC_RELAXED, __HIP_MEMORY_SCOPE_AGENT);
    int batch = s >> 4;
    if ((s & 15) == 15) {  // 16th same-XCD registrant completes a batch -> claim group
      int gid = __hip_atomic_fetch_add(&reg[1], 1, __ATOMIC_RELAXED, __HIP_MEMORY_SCOPE_AGENT);
      __hip_atomic_store(&reg[64 + (int)xcc * 16 + batch], (gid < 4) ? gid : 99,
                         __ATOMIC_RELAXED, __HIP_MEMORY_SCOPE_AGENT);
    }
    __hip_atomic_fetch_add(&reg[0], 1, __ATOMIC_RELEASE, __HIP_MEMORY_SCOPE_AGENT);
    while (__hip_atomic_load(&reg[0], __ATOMIC_ACQUIRE, __HIP_MEMORY_SCOPE_AGENT) < 256) {}
    sh_gid = __hip_atomic_load(&reg[64 + (int)xcc * 16 + batch],
                               __ATOMIC_RELAXED, __HIP_MEMORY_SCOPE_AGENT);
    sh_m = s & 15;
  }
  __syncthreads();
  const int gid = sh_gid;
  const int m = sh_m;
  if (gid < 0 || gid >= 4) return;  // incomplete batch (-1) or surplus group (99)

  const int lane = tid & 63;
  const int wave = tid >> 6;
  const int q = lane >> 4;
  const int c = lane & 15;
  const int jb = m * 32;
  const int wcol = wave * 16;

  if (gid == 0 && m == 0) {
    for (int i = tid; i < N_H; i += 128) out[N_B * N_IN + i] = HID[i];
  }

  // ---- stage weight slice into LDS (f32 -> bf16), transposed + swizzled ----
  for (int idx = tid; idx < 96 * 768; idx += 128) {
    int k = idx / 96, r = idx - k * 96;
    int g3 = r >> 5, cc = r & 31;
    const float* W = (g3 == 0) ? Wi : ((g3 == 1) ? Wg : Wo);
    unsigned short v = f2bf(W[k * N_H + jb + cc]);
    int byte = (r * 1536 + k * 2) ^ ((r & 7) << 4);  // XOR swizzle (G4)
    *(unsigned short*)((char*)ldsw + byte) = v;
  }
  __syncthreads();  // only block barrier (weights read-only afterwards)

  auto ldb = [&](int gg, int kt) -> bf16x8 {
    int r = gg * 32 + wcol + c;
    int byte = (r * 1536 + kt * 64 + q * 16) ^ ((r & 7) << 4);
    return *(const bf16x8*)((const char*)ldsw + byte);
  };

  const float Bi = bi[jb + wcol + c];
  const float Bg = bg[jb + wcol + c];
  const float Bo = bo[jb + wcol + c];
  const float* xrow = X + (size_t)(gid * 16 + c) * (T_LEN * N_IN);

  char* const gf = (char*)hbF + gid * 65536;  // fast (sc0/L2) group base, bytes
  char* const gs = (char*)hbS + gid * 65536;  // slow (agent/LLC) group base
  const int roff64 = (q >> 1) * 64 + c * 4 + (q & 1) * 2;           // u64 idx in buf
  const int vbr = (q >> 1) * 512 + c * 32 + (q & 1) * 16;           // same, bytes
  const int swr = wave * 384;
  const int srb = wave * 384 + (lane >> 2) * 24 + (lane & 3) * 4;
  const unsigned long long TAGM = 0x0000000100000001ull;
  bool slow = !dual;  // single-buffer mode starts (and stays) on the proven path

  #pragma unroll 1
  for (int t = 0; t < T_LEN; ++t) {
    // ---- (a) x-part GEMM ----
    f32x4 ai = {0.f, 0.f, 0.f, 0.f};
    f32x4 ag = {0.f, 0.f, 0.f, 0.f};
    f32x4 ao = {0.f, 0.f, 0.f, 0.f};
    const float* xp = xrow + (size_t)t * N_IN + q * 8;
    #pragma unroll
    for (int kk = 0; kk < 8; ++kk) {
      bf16x8 a = cvt8(xp + kk * 32);
      ai = __builtin_amdgcn_mfma_f32_16x16x32_bf16(a, ldb(0, kk), ai, 0, 0, 0);
      ag = __builtin_amdgcn_mfma_f32_16x16x32_bf16(a, ldb(1, kk), ag, 0, 0, 0);
      ao = __builtin_amdgcn_mfma_f32_16x16x32_bf16(a, ldb(2, kk), ao, 0, 0, 0);
    }

    // ---- (b) tag-validated h_t loads: sc0/L2 first, watchdog -> agent/LLC ----
    unsigned long long hreg[32];
    const unsigned long long want = ((t >> 2) & 1) ? TAGM : 0ull;
    bool got = false;
    if (!slow) {
      const char* fb = gf + (t & 3) * 16384;
      for (int tries = 0; tries < 4096 && !got; ++tries) {
        i32x4 f[16];
        ld_h16_sc0(fb, vbr, f);
        bool ok = true;
        #pragma unroll
        for (int kk = 0; kk < 16; ++kk) {
          union { i32x4 i; unsigned long long u[2]; } w; w.i = f[kk];
          hreg[2 * kk] = w.u[0]; hreg[2 * kk + 1] = w.u[1];
          ok &= ((w.u[0] & TAGM) == want) & ((w.u[1] & TAGM) == want);
        }
        if (__all(ok)) got = true;
      }
      if (!got) slow = true;  // sticky fallback; producers dual-publish so this is safe
    }
    if (!got) {
      const unsigned long long* hb64 = (const unsigned long long*)(void*)(gs + (t & 3) * 16384);
      for (;;) {
        #pragma unroll
        for (int kk = 0; kk < 16; ++kk) {
          hreg[2 * kk]     = __hip_atomic_load(hb64 + kk * 128 + roff64,
                                               __ATOMIC_RELAXED, __HIP_MEMORY_SCOPE_AGENT);
          hreg[2 * kk + 1] = __hip_atomic_load(hb64 + kk * 128 + roff64 + 1,
                                               __ATOMIC_RELAXED, __HIP_MEMORY_SCOPE_AGENT);
        }
        bool ok = true;
        #pragma unroll
        for (int i = 0; i < 32; ++i) ok &= ((hreg[i] & TAGM) == want);
        if (__all(ok)) break;
      }
    }

    // ---- (c) h-part GEMM ----
    #pragma unroll
    for (int kk = 0; kk < 16; ++kk) {
      union { unsigned long long u[2]; bf16x8 v; } a;
      a.u[0] = hreg[2 * kk]; a.u[1] = hreg[2 * kk + 1];
      ai = __builtin_amdgcn_mfma_f32_16x16x32_bf16(a.v, ldb(0, kk + 8), ai, 0, 0, 0);
      ag = __builtin_amdgcn_mfma_f32_16x16x32_bf16(a.v, ldb(1, kk + 8), ag, 0, 0, 0);
      ao = __builtin_amdgcn_mfma_f32_16x16x32_bf16(a.v, ldb(2, kk + 8), ao, 0, 0, 0);
    }

    // ---- (d) nonlinearity (tag even cols) -> scratch -> dual-publish ----
    const unsigned short tau1 = (unsigned short)(((t + 1) >> 2) & 1);
    #pragma unroll
    for (int j = 0; j < 4; ++j) {
      float iv = sigm(ai[j] + Bi);
      float gv = tanh_(ag[j] + Bg);
      float ov = sigm(ao[j] + Bo);
      float h = ov * tanh_(iv * gv);
      unsigned short hv = f2bf(h);
      if ((c & 1) == 0) hv = (unsigned short)((hv & 0xFFFEu) | tau1);
      ldsh[swr + (q * 4 + j) * 24 + c] = hv;  // D: col=lane&15, row=q*4+j (m89)
    }
    asm volatile("s_waitcnt lgkmcnt(0)" ::: "memory");  // r14 lesson
    {
      unsigned long long v64;
      __builtin_memcpy(&v64, (const void*)(ldsh + srb), 8);
      st_u64_sc0(gf + ((t + 1) & 3) * 16384, m * 1024 + tid * 8, v64);
      unsigned long long* ds =
          (unsigned long long*)(void*)(gs + ((t + 1) & 3) * 16384) + m * 128 + tid;
      __hip_atomic_store(ds, v64, __ATOMIC_RELAXED, __HIP_MEMORY_SCOPE_AGENT);
    }
  }

  // ---- epilogue: out = h_T @ W_out + b_out ; h_T in buf 0, tag 0 ----
  if (wave == 0) {
    unsigned long long he[32];
    bool got = false;
    if (!slow) {
      for (int tries = 0; tries < 4096 && !got; ++tries) {
        i32x4 f[16];
        ld_h16_sc0(gf, vbr, f);
        bool ok = true;
        #pragma unroll
        for (int kk = 0; kk < 16; ++kk) {
          union { i32x4 i; unsigned long long u[2]; } w; w.i = f[kk];
          he[2 * kk] = w.u[0]; he[2 * kk + 1] = w.u[1];
          ok &= ((w.u[0] & TAGM) == 0ull) & ((w.u[1] & TAGM) == 0ull);
        }
        if (__all(ok)) got = true;
      }
    }
    if (!got) {
      const unsigned long long* hb64 = (const unsigned long long*)(void*)gs;
      for (;;) {
        #pragma unroll
        for (int kk = 0; kk < 16; ++kk) {
          he[2 * kk]     = __hip_atomic_load(hb64 + kk * 128 + roff64,
                                             __ATOMIC_RELAXED, __HIP_MEMORY_SCOPE_AGENT);
          he[2 * kk + 1] = __hip_atomic_load(hb64 + kk * 128 + roff64 + 1,
                                             __ATOMIC_RELAXED, __HIP_MEMORY_SCOPE_AGENT);
        }
        bool ok = true;
        #pragma unroll
        for (int i = 0; i < 32; ++i) ok &= ((he[i] & TAGM) == 0ull);
        if (__all(ok)) break;
      }
    }
    f32x4 acc = {0.f, 0.f, 0.f, 0.f};
    #pragma unroll 4
    for (int kk = 0; kk < 16; ++kk) {
      union { unsigned long long u[2]; bf16x8 v; } a;
      a.u[0] = he[2 * kk]; a.u[1] = he[2 * kk + 1];
      union { bf16x8 v; unsigned short u[8]; } bb;
      #pragma unroll
      for (int j = 0; j < 8; ++j)
        bb.u[j] = f2bf(Wout[(size_t)(kk * 32 + q * 8 + j) * N_IN + m * 16 + c]);
      acc = __builtin_amdgcn_mfma_f32_16x16x32_bf16(a.v, bb.v, acc, 0, 0, 0);
    }
    const float Bb = bout[m * 16 + c];
    #pragma unroll
    for (int j = 0; j < 4; ++j) {
      int row = q * 4 + j;
      out[(gid * 16 + row) * N_IN + m * 16 + c] = acc[j] + Bb;
    }
  }
}

extern "C" void kernel_launch(void* const* d_in, const int* in_sizes, int n_in,
                              void* d_out, int out_size, void* d_ws, size_t ws_size,
                              hipStream_t stream) {
  const float* X    = (const float*)d_in[0];
  const float* HID  = (const float*)d_in[1];
  const float* Wi   = (const float*)d_in[2];
  const float* bi   = (const float*)d_in[3];
  const float* Wg   = (const float*)d_in[4];
  const float* bg   = (const float*)d_in[5];
  const float* Wo   = (const float*)d_in[6];
  const float* bo   = (const float*)d_in[7];
  const float* Wout = (const float*)d_in[8];
  const float* bout = (const float*)d_in[9];

  const size_t SET = 262144;  // 4 groups x 4 bufs x 16384 B
  int dual = (ws_size >= 4096 + 2 * SET) ? 1 : 0;
  int* regp = (int*)d_ws;
  unsigned short* hbF = (unsigned short*)((char*)d_ws + 4096);
  unsigned short* hbS = dual ? (unsigned short*)((char*)d_ws + 4096 + SET) : hbF;

  int nInts = (int)((4096 + (dual ? 2 : 1) * SET) / 4);
  lstm_init<<<dim3((nInts + 255) / 256), dim3(256), 0, stream>>>((int*)d_ws, nInts);
  lstm_persist<<<dim3(256), dim3(128), 96 * 768 * 2 + 1536, stream>>>(
      X, HID, Wi, bi, Wg, bg, Wo, bo, Wout, bout,
      (float*)d_out, hbF, hbS, regp, dual);
}

// Round 19
// 7203.082 us; speedup vs baseline: 2.3905x; 2.3905x over previous
//
#include <hip/hip_runtime.h>
#include <hip/hip_bf16.h>

#define T_LEN 2048
#define N_IN 256
#define N_H 512
#define N_B 64

typedef float f32x4 __attribute__((ext_vector_type(4)));
typedef __bf16 bf16x8 __attribute__((ext_vector_type(8)));

__device__ __forceinline__ unsigned short f2bf(float f) {
  union { float f; unsigned int i; } x; x.f = f;
  unsigned int r = x.i + 0x7fffu + ((x.i >> 16) & 1u);  // RNE
  return (unsigned short)(r >> 16);
}
__device__ __forceinline__ float sigm(float x) { return 1.0f / (1.0f + __expf(-x)); }
__device__ __forceinline__ float tanh_(float x) {
  float a = fabsf(x);
  float e = __expf(2.0f * a);
  float r = 1.0f - 2.0f / (e + 1.0f);
  return copysignf(r, x);
}
// convert two f32x4 (8 consecutive f32) -> bf16x8 (RNE)
__device__ __forceinline__ bf16x8 cvt8r(f32x4 a, f32x4 b) {
  union { bf16x8 v; unsigned short u[8]; } r;
  #pragma unroll
  for (int j = 0; j < 4; ++j) { r.u[j] = f2bf(a[j]); r.u[j + 4] = f2bf(b[j]); }
  return r.v;
}

// ws layout: hbuf u16 only (NO FLAGS — tags inside the data are the sole sync):
//   [group 4][buf 4][slice 16][whalf 2][brow 16][hcol 16]
// group stride 32768 u16, buf stride 8192 u16. Even-hcol u16s carry tag in bf16
// LSB; h_t lives in buf t&3 with tag tau(t) = (t>>2)&1. Init: buf 0 = 0x0000
// (real h0, tag 0 valid for t=0); bufs 1..3 = 0x0001 (tag 1, invalid first cycle).
__global__ void lstm_init(int* __restrict__ ws) {
  int i = blockIdx.x * 256 + threadIdx.x;  // grid 256 -> 65536 ints = 256 KB
  ws[i] = ((i & 16383) < 4096) ? 0 : 0x00010001;
}

// 64 WGs x 128 threads. Group g = bid&3 owns batch rows 16g..16g+15 (independent
// recurrence). Member m = bid>>2 owns hidden cols 32m..32m+31; wave w owns 16.
// Zero barriers/flags in main loop (tag-validated loads). NEW vs r17: one-step
// x register prefetch — x HBM latency overlaps the h-load round-trip.
__global__ __launch_bounds__(128, 1) void lstm_persist(
    const float* __restrict__ X,     // [64, 2048, 256] f32
    const float* __restrict__ HID,   // [1, 512] f32 (passthrough)
    const float* __restrict__ Wi, const float* __restrict__ bi,
    const float* __restrict__ Wg, const float* __restrict__ bg,
    const float* __restrict__ Wo, const float* __restrict__ bo,
    const float* __restrict__ Wout, const float* __restrict__ bout,
    float* __restrict__ out,                  // f32: [64*256] + [512]
    unsigned short* __restrict__ hbuf)
{
  extern __shared__ unsigned short ldsw[];  // 96*768 swizzled weights + 768 u16 scratch
  unsigned short* ldsh = ldsw + 96 * 768;   // per-wave [16 brow][24 pad] u16
  const int tid = threadIdx.x;
  const int b = blockIdx.x;
  const int g = b & 3;
  const int m = b >> 2;
  const int lane = tid & 63;
  const int wave = tid >> 6;
  const int q = lane >> 4;
  const int c = lane & 15;
  const int jb = m * 32;
  const int wcol = wave * 16;

  if (b == 0) {
    for (int i = tid; i < N_H; i += 128) out[N_B * N_IN + i] = HID[i];
  }

  // ---- stage weight slice into LDS (f32 -> bf16), transposed + swizzled ----
  for (int idx = tid; idx < 96 * 768; idx += 128) {
    int k = idx / 96, r = idx - k * 96;
    int g3 = r >> 5, cc = r & 31;
    const float* W = (g3 == 0) ? Wi : ((g3 == 1) ? Wg : Wo);
    unsigned short v = f2bf(W[k * N_H + jb + cc]);
    int byte = (r * 1536 + k * 2) ^ ((r & 7) << 4);  // XOR swizzle (G4)
    *(unsigned short*)((char*)ldsw + byte) = v;
  }
  __syncthreads();  // only block-wide barrier (weights read-only afterwards)

  auto ldb = [&](int gg, int kt) -> bf16x8 {
    int r = gg * 32 + wcol + c;
    int byte = (r * 1536 + kt * 64 + q * 16) ^ ((r & 7) << 4);
    return *(const bf16x8*)((const char*)ldsw + byte);
  };

  const float Bi = bi[jb + wcol + c];
  const float Bg = bg[jb + wcol + c];
  const float Bo = bo[jb + wcol + c];

  const float* xrow = X + (size_t)(g * 16 + c) * (T_LEN * N_IN);

  unsigned short* gh0 = hbuf + g * 32768;                  // group base (u16)
  const int roff64 = (q >> 1) * 64 + c * 4 + (q & 1) * 2;  // reader u64 idx in buf
  const int swr = wave * 384;
  const int srb = wave * 384 + (lane >> 2) * 24 + (lane & 3) * 4;
  const unsigned long long TAGM = 0x0000000100000001ull;   // LSB of each dword

  // ---- x prefetch registers: raw f32 for the CURRENT step (loaded last step) ----
  f32x4 xr[16];
  {
    const float* xp = xrow + q * 8;  // t = 0
    #pragma unroll
    for (int kk = 0; kk < 8; ++kk) {
      xr[2 * kk]     = *(const f32x4*)(const void*)(xp + kk * 32);
      xr[2 * kk + 1] = *(const f32x4*)(const void*)(xp + kk * 32 + 4);
    }
  }

  #pragma unroll 1
  for (int t = 0; t < T_LEN; ++t) {
    // ---- (a) x-part GEMM from prefetched registers (no HBM wait in chain) ----
    f32x4 ai = {0.f, 0.f, 0.f, 0.f};
    f32x4 ag = {0.f, 0.f, 0.f, 0.f};
    f32x4 ao = {0.f, 0.f, 0.f, 0.f};
    #pragma unroll
    for (int kk = 0; kk < 8; ++kk) {
      bf16x8 a = cvt8r(xr[2 * kk], xr[2 * kk + 1]);
      ai = __builtin_amdgcn_mfma_f32_16x16x32_bf16(a, ldb(0, kk), ai, 0, 0, 0);
      ag = __builtin_amdgcn_mfma_f32_16x16x32_bf16(a, ldb(1, kk), ag, 0, 0, 0);
      ao = __builtin_amdgcn_mfma_f32_16x16x32_bf16(a, ldb(2, kk), ao, 0, 0, 0);
    }

    // ---- (b) issue h_t loads, then x(t+1) prefetch (overlaps the h round-trip) ----
    const unsigned long long* hb64 =
        (const unsigned long long*)(gh0 + (size_t)(t & 3) * 8192);
    unsigned long long hreg[32];
    #pragma unroll
    for (int kk = 0; kk < 16; ++kk) {
      hreg[2 * kk]     = __hip_atomic_load(hb64 + kk * 128 + roff64,
                                           __ATOMIC_RELAXED, __HIP_MEMORY_SCOPE_AGENT);
      hreg[2 * kk + 1] = __hip_atomic_load(hb64 + kk * 128 + roff64 + 1,
                                           __ATOMIC_RELAXED, __HIP_MEMORY_SCOPE_AGENT);
    }
    {
      int tn = (t + 1 < T_LEN) ? t + 1 : t;  // clamped (last-step result unused)
      const float* xp = xrow + (size_t)tn * N_IN + q * 8;
      #pragma unroll
      for (int kk = 0; kk < 8; ++kk) {
        xr[2 * kk]     = *(const f32x4*)(const void*)(xp + kk * 32);
        xr[2 * kk + 1] = *(const f32x4*)(const void*)(xp + kk * 32 + 4);
      }
    }

    // ---- (c) validate tags; retry reloads h only (xr already landed) ----
    {
      const unsigned long long want = ((t >> 2) & 1) ? TAGM : 0ull;
      for (;;) {
        bool ok = true;
        #pragma unroll
        for (int i = 0; i < 32; ++i) ok &= ((hreg[i] & TAGM) == want);
        if (__all(ok)) break;
        #pragma unroll
        for (int kk = 0; kk < 16; ++kk) {
          hreg[2 * kk]     = __hip_atomic_load(hb64 + kk * 128 + roff64,
                                               __ATOMIC_RELAXED, __HIP_MEMORY_SCOPE_AGENT);
          hreg[2 * kk + 1] = __hip_atomic_load(hb64 + kk * 128 + roff64 + 1,
                                               __ATOMIC_RELAXED, __HIP_MEMORY_SCOPE_AGENT);
        }
      }
    }

    // ---- (d) h-part GEMM ----
    #pragma unroll
    for (int kk = 0; kk < 16; ++kk) {
      union { unsigned long long u[2]; bf16x8 v; } a;
      a.u[0] = hreg[2 * kk]; a.u[1] = hreg[2 * kk + 1];
      ai = __builtin_amdgcn_mfma_f32_16x16x32_bf16(a.v, ldb(0, kk + 8), ai, 0, 0, 0);
      ag = __builtin_amdgcn_mfma_f32_16x16x32_bf16(a.v, ldb(1, kk + 8), ag, 0, 0, 0);
      ao = __builtin_amdgcn_mfma_f32_16x16x32_bf16(a.v, ldb(2, kk + 8), ao, 0, 0, 0);
    }

    // ---- (e) nonlinearity (tag even cols) -> scratch -> u64 store to buf (t+1)&3 ----
    // Write-safety (no flags): validating h_t proves every wave issued its h_t
    // store => finished its step t-1 reads => a fortiori its t-3 reads of buf (t+1)&3.
    const unsigned short tau1 = (unsigned short)(((t + 1) >> 2) & 1);
    #pragma unroll
    for (int j = 0; j < 4; ++j) {
      float iv = sigm(ai[j] + Bi);
      float gv = tanh_(ag[j] + Bg);
      float ov = sigm(ao[j] + Bo);
      float h = ov * tanh_(iv * gv);
      unsigned short hv = f2bf(h);
      if ((c & 1) == 0) hv = (unsigned short)((hv & 0xFFFEu) | tau1);  // step tag
      ldsh[swr + (q * 4 + j) * 24 + c] = hv;  // D: col=lane&15, row=q*4+j (m89)
    }
    // ordering fix (r14 lesson): fence compiler + wait own LDS writes
    asm volatile("s_waitcnt lgkmcnt(0)" ::: "memory");
    {
      unsigned long long v64;
      __builtin_memcpy(&v64, (const void*)(ldsh + srb), 8);
      unsigned long long* hn =
          (unsigned long long*)(gh0 + (size_t)((t + 1) & 3) * 8192) + m * 128 + tid;
      __hip_atomic_store(hn, v64, __ATOMIC_RELAXED, __HIP_MEMORY_SCOPE_AGENT);
    }
  }

  // ---- epilogue: out = h_T @ W_out + b_out ; h_T in buf 2048&3 = 0, tag 0 ----
  if (wave == 0) {
    const unsigned long long* hb64 = (const unsigned long long*)gh0;
    unsigned long long he[32];
    for (;;) {
      #pragma unroll
      for (int kk = 0; kk < 16; ++kk) {
        he[2 * kk]     = __hip_atomic_load(hb64 + kk * 128 + roff64,
                                           __ATOMIC_RELAXED, __HIP_MEMORY_SCOPE_AGENT);
        he[2 * kk + 1] = __hip_atomic_load(hb64 + kk * 128 + roff64 + 1,
                                           __ATOMIC_RELAXED, __HIP_MEMORY_SCOPE_AGENT);
      }
      bool ok = true;
      #pragma unroll
      for (int i = 0; i < 32; ++i) ok &= ((he[i] & TAGM) == 0ull);
      if (__all(ok)) break;
    }
    f32x4 acc = {0.f, 0.f, 0.f, 0.f};
    #pragma unroll 4
    for (int kk = 0; kk < 16; ++kk) {
      union { unsigned long long u[2]; bf16x8 v; } a;
      a.u[0] = he[2 * kk]; a.u[1] = he[2 * kk + 1];
      union { bf16x8 v; unsigned short u[8]; } bb;
      #pragma unroll
      for (int j = 0; j < 8; ++j)
        bb.u[j] = f2bf(Wout[(size_t)(kk * 32 + q * 8 + j) * N_IN + m * 16 + c]);
      acc = __builtin_amdgcn_mfma_f32_16x16x32_bf16(a.v, bb.v, acc, 0, 0, 0);
    }
    const float Bb = bout[m * 16 + c];
    #pragma unroll
    for (int j = 0; j < 4; ++j) {
      int row = q * 4 + j;
      out[(g * 16 + row) * N_IN + m * 16 + c] = acc[j] + Bb;
    }
  }
}

extern "C" void kernel_launch(void* const* d_in, const int* in_sizes, int n_in,
                              void* d_out, int out_size, void* d_ws, size_t ws_size,
                              hipStream_t stream) {
  const float* X    = (const float*)d_in[0];
  const float* HID  = (const float*)d_in[1];
  const float* Wi   = (const float*)d_in[2];
  const float* bi   = (const float*)d_in[3];
  const float* Wg   = (const float*)d_in[4];
  const float* bg   = (const float*)d_in[5];
  const float* Wo   = (const float*)d_in[6];
  const float* bo   = (const float*)d_in[7];
  const float* Wout = (const float*)d_in[8];
  const float* bout = (const float*)d_in[9];

  unsigned short* hbuf = (unsigned short*)d_ws;  // 256 KB

  lstm_init<<<dim3(256), dim3(256), 0, stream>>>((int*)d_ws);
  lstm_persist<<<dim3(64), dim3(128), 96 * 768 * 2 + 1536, stream>>>(
      X, HID, Wi, bi, Wg, bg, Wo, bo, Wout, bout,
      (float*)d_out, hbuf);
}